// Round 5
// baseline (1116.342 us; speedup 1.0000x reference)
//
#include <hip/hip_runtime.h>

// GraphCNN fused per-graph MFMA kernel (fp16 inputs, fp32 accumulate).
// One workgroup (256 thr = 4 waves) per graph; 4 blocks/CU (LDS 40,320 B).
// Key changes vs prev: LDS cut 46,080 -> 40,320 for 4 blocks/CU:
//   - B1 now [90][128] f16 with row-XOR swizzle (half8 idx ^= row&7) --
//     restores the 8-start conflict-free bank pattern of the old 136 stride.
//   - adjH split into A1 [90][64] + A2 [90][32], each row-XOR swizzled
//     (closed within their slots/row). Pad rows 90..95 eliminated: reads
//     clamp row to <=89 (finite garbage -> discarded/zero-multiplied),
//     writes for node>=90 exec-masked off. adj cols 90..95 stay zeroed.
// Algebraic structure unchanged from R2 (Wd/We folds, in-register frags).
//
// MFMA layouts (gfx950, verified learn_hip m74/m101/m120):
//   A: A[m][k], m = lane&31, k = (lane>>5)*8 + j   (8 contiguous k -> b128)
//   B: B[k][n], n = lane&31, k = (lane>>5)*8 + j
//   C/D: col = lane&31, row = (reg&3) + 8*(reg>>2) + 4*(lane>>5)

#define NN 90
#define HH 128
#define NT 256

typedef _Float16 half8 __attribute__((ext_vector_type(8)));
typedef _Float16 half2v __attribute__((ext_vector_type(2)));
typedef float floatx16 __attribute__((ext_vector_type(16)));
typedef unsigned int uint4v __attribute__((ext_vector_type(4)));

#define MFMA(a, b, c) __builtin_amdgcn_mfma_f32_32x32x16_f16((a), (b), (c), 0, 0, 0)

// ---------------- weight prep ----------------
// ws layout (f16 elems): W0T [128][96] @0 | WdT [128][96] @12288 (col90 = c1)
//   | WeT [128][96] @24576 (col90 = bsum) | W1T [128][128] @36864
//   | W2T [128][128] @53248.  End f16 @69632 (139,264 B).
// fp32 scratch: WdF [90][128] @byte 139264 ; c1F [128] @byte 185344.
__global__ void prep_stage1(const float* __restrict__ W0,
                            const float* __restrict__ Wr1,
                            const float* __restrict__ b0,
                            const float* __restrict__ br1,
                            float* __restrict__ WdF,
                            float* __restrict__ c1F)
{
    const int idx = blockIdx.x * blockDim.x + threadIdx.x;
    if (idx < NN * HH) {                 // Wd[k][n] = sum_q W0[k][q] Wr1[q][n]
        const int k = idx >> 7, nn = idx & 127;
        float s = 0.f;
        for (int q = 0; q < HH; q++) s += W0[k * HH + q] * Wr1[q * HH + nn];
        WdF[idx] = s;
    } else if (idx < NN * HH + HH) {     // c1[n] = b0@Wr1 + br1
        const int nn = idx - NN * HH;
        float s = br1[nn];
        for (int q = 0; q < HH; q++) s += b0[q] * Wr1[q * HH + nn];
        c1F[nn] = s;
    }
}

__global__ void prep_stage2(const float* __restrict__ W0,
                            const float* __restrict__ W1,
                            const float* __restrict__ W2,
                            const float* __restrict__ Wr2,
                            const float* __restrict__ b2,
                            const float* __restrict__ br2,
                            const float* __restrict__ WdF,
                            const float* __restrict__ c1F,
                            _Float16* __restrict__ ws)
{
    const int idx = blockIdx.x * blockDim.x + threadIdx.x;
    if (idx < 12288) {                       // W0T[n][k], k padded 90->96 w/ zeros
        const int nn = idx / 96, k = idx - nn * 96;
        ws[idx] = (k < NN) ? (_Float16)W0[k * HH + nn] : (_Float16)0.f;
    } else if (idx < 24576) {                // WdT[n][k]; col 90 = c1[n]
        const int j = idx - 12288;
        const int nn = j / 96, k = j - nn * 96;
        _Float16 v = (_Float16)0.f;
        if (k < NN)       v = (_Float16)WdF[k * HH + nn];
        else if (k == NN) v = (_Float16)c1F[nn];
        ws[idx] = v;
    } else if (idx < 36864) {                // WeT[n][k] = (Wd@Wr2)[k][n]; col90=bsum
        const int j = idx - 24576;
        const int nn = j / 96, k = j - nn * 96;
        _Float16 v = (_Float16)0.f;
        if (k < NN) {
            float s = 0.f;
            for (int q = 0; q < HH; q++) s += WdF[k * HH + q] * Wr2[q * HH + nn];
            v = (_Float16)s;
        } else if (k == NN) {                // bsum = b2 + br2 + c1@Wr2
            float s = b2[nn] + br2[nn];
            for (int q = 0; q < HH; q++) s += c1F[q] * Wr2[q * HH + nn];
            v = (_Float16)s;
        }
        ws[idx] = v;
    } else if (idx < 53248) {                // W1T [128][128]
        const int j = idx - 36864;
        const int nn = j >> 7, k = j & 127;
        ws[idx] = (_Float16)W1[k * HH + nn];
    } else if (idx < 69632) {                // W2T [128][128]
        const int j = idx - 53248;
        const int nn = j >> 7, k = j & 127;
        ws[idx] = (_Float16)W2[k * HH + nn];
    }
}

// ---------------- main fused kernel ----------------
__global__ __launch_bounds__(NT, 4) void graphcnn_mfma(
    const float* __restrict__ adj,
    const _Float16* __restrict__ wts,
    const float* __restrict__ b0, const float* __restrict__ b1,
    float* __restrict__ out)
{
    // LDS: A1 [90][64] swz | A2 [90][32] swz | B1 [90][128] swz (tR->uR->YR)
    __shared__ __align__(16) unsigned char smem[40320];
    _Float16* adj1 = (_Float16*)smem;                 // 11,520 B
    _Float16* adj2 = (_Float16*)(smem + 11520);       //  5,760 B
    _Float16* B1   = (_Float16*)(smem + 17280);       // 23,040 B

    const int t    = threadIdx.x;
    const int wv   = t >> 6;
    const int lane = t & 63;
    const int p    = lane & 31;
    const int h    = lane >> 5;
    const int n    = wv * 32 + p;      // hidden column owned by this thread

    const _Float16* W0T = wts;                  // [128][96]
    const _Float16* WdT = wts + 12288;          // [128][96], col90 = c1
    const _Float16* WeT = wts + 24576;          // [128][96], col90 = bsum
    const _Float16* W1T = wts + 36864;          // [128][128]
    const _Float16* W2T = wts + 53248;          // [128][128]

    // clamped A-operand rows (rows 90..95 -> 89: finite garbage, outputs masked)
    const int r0 = p;
    const int r1 = 32 + p;
    const int r2 = (64 + p > 89) ? 89 : (64 + p);

    // ---- stage adj fp32->fp16, swizzled, cols 90..95 zeroed ----
    {
        const float* Ag = adj + (size_t)blockIdx.x * (NN * NN);
        unsigned* a1u = (unsigned*)adj1;
        unsigned* a2u = (unsigned*)adj2;
        #pragma unroll
        for (int it = 0; it < 17; it++) {
            const int i = t + it * NT;          // 0..4319 = 90 rows * 48 dw
            if (i < 4320) {
                const int r = i / 48, cc = i - r * 48;
                unsigned val = 0u;
                if (cc < 45) {
                    const float2 v = *(const float2*)(Ag + r * NN + cc * 2);
                    const half2v hv = { (_Float16)v.x, (_Float16)v.y };
                    val = __builtin_bit_cast(unsigned, hv);
                }
                if (cc < 32) a1u[r * 32 + (cc ^ ((r & 7) << 2))] = val;
                else         a2u[r * 16 + ((cc - 32) ^ ((r & 3) << 2))] = val;
            }
        }
    }

    // swizzled read helpers (kt is compile-time constant at call sites)
    auto rdA = [&](int row, int kt) -> half8 {
        if (kt < 4)
            return ((const half8*)adj1)[row * 8 + (((kt * 2 + h)) ^ (row & 7))];
        else
            return ((const half8*)adj2)[row * 4 + (((kt - 4) * 2 + h) ^ (row & 3))];
    };
    auto rdB = [&](int row, int kt) -> half8 {
        return ((const half8*)B1)[row * 16 + ((kt * 2 + h) ^ (row & 7))];
    };

    // C-registers -> row-major swizzled LDS (nodes >= 90 dropped)
    auto writeR = [&](const floatx16& A0, const floatx16& A1f,
                      const floatx16& A2f) {
        #pragma unroll
        for (int mt = 0; mt < 3; mt++) {
            const floatx16& A = (mt == 0) ? A0 : (mt == 1) ? A1f : A2f;
            #pragma unroll
            for (int r = 0; r < 16; r++) {
                const int node = mt * 32 + (r & 3) + 8 * (r >> 2) + 4 * h;
                if (node < NN)
                    B1[node * 128 + (n ^ ((node & 7) << 3))] = (_Float16)A[r];
            }
        }
    };

    // C-registers -> B-fragments (for next adj@X matmul), pure in-register:
    // consumer lane (p,h) needs B[k=16kt+8h+j][n]; exchange across lane^32.
    uint4v frg[6];
    auto buildFrags = [&](const floatx16& A0, const floatx16& A1f,
                          const floatx16& A2f) {
        #pragma unroll
        for (int mt = 0; mt < 3; mt++) {
            const floatx16& A = (mt == 0) ? A0 : (mt == 1) ? A1f : A2f;
            #pragma unroll
            for (int s01 = 0; s01 < 2; s01++) {
                const int s = 8 * s01;
                const half2v x0 = { (_Float16)A[s + 0], (_Float16)A[s + 1] };
                const half2v x1 = { (_Float16)A[s + 2], (_Float16)A[s + 3] };
                const half2v y0 = { (_Float16)A[s + 4], (_Float16)A[s + 5] };
                const half2v y1 = { (_Float16)A[s + 6], (_Float16)A[s + 7] };
                const unsigned X0 = __builtin_bit_cast(unsigned, x0);
                const unsigned X1 = __builtin_bit_cast(unsigned, x1);
                const unsigned Y0 = __builtin_bit_cast(unsigned, y0);
                const unsigned Y1 = __builtin_bit_cast(unsigned, y1);
                const unsigned R0 = __shfl_xor(h ? X0 : Y0, 32, 64);
                const unsigned R1 = __shfl_xor(h ? X1 : Y1, 32, 64);
                uint4v f;
                f[0] = h ? R0 : X0;
                f[1] = h ? R1 : X1;
                f[2] = h ? Y0 : R0;
                f[3] = h ? Y1 : R1;
                frg[mt * 2 + s01] = f;
            }
        }
    };

    __syncthreads();

    floatx16 acc0, acc1, acc2;

    // ===== S1: h0 = adj @ W0 + b0 -> B-frags only (no LDS write) =====
    {
        half8 bw[6];
        #pragma unroll
        for (int kt = 0; kt < 6; kt++) bw[kt] = ((const half8*)W0T)[n * 12 + kt * 2 + h];
        const float bias = b0[n];
        #pragma unroll
        for (int r = 0; r < 16; r++) { acc0[r] = bias; acc1[r] = bias; acc2[r] = bias; }
        #pragma unroll
        for (int kt = 0; kt < 6; kt++) {
            acc0 = MFMA(rdA(r0, kt), bw[kt], acc0);
            acc1 = MFMA(rdA(r1, kt), bw[kt], acc1);
            acc2 = MFMA(rdA(r2, kt), bw[kt], acc2);
        }
        buildFrags(acc0, acc1, acc2);
    }

    // ===== S3: t = adj @ h0 (B from regs) -> tR (B1) =====
    {
        #pragma unroll
        for (int r = 0; r < 16; r++) { acc0[r] = 0.f; acc1[r] = 0.f; acc2[r] = 0.f; }
        #pragma unroll
        for (int kt = 0; kt < 6; kt++) {
            const half8 bfk = __builtin_bit_cast(half8, frg[kt]);
            acc0 = MFMA(rdA(r0, kt), bfk, acc0);
            acc1 = MFMA(rdA(r1, kt), bfk, acc1);
            acc2 = MFMA(rdA(r2, kt), bfk, acc2);
        }
        writeR(acc0, acc1, acc2);
    }

    // ===== S2': r1 = adj @ Wd + c1 -> packed fp16 regs =====
    half8 r1p[6];
    {
        half8 bw[6];
        #pragma unroll
        for (int kt = 0; kt < 6; kt++) bw[kt] = ((const half8*)WdT)[n * 12 + kt * 2 + h];
        const float bias = (float)WdT[n * 96 + 90];      // c1[n]
        floatx16 ra, rb, rc;
        #pragma unroll
        for (int r = 0; r < 16; r++) { ra[r] = bias; rb[r] = bias; rc[r] = bias; }
        #pragma unroll
        for (int kt = 0; kt < 6; kt++) {
            ra = MFMA(rdA(r0, kt), bw[kt], ra);
            rb = MFMA(rdA(r1, kt), bw[kt], rb);
            rc = MFMA(rdA(r2, kt), bw[kt], rc);
        }
        #pragma unroll
        for (int mt = 0; mt < 3; mt++) {
            const floatx16& A = (mt == 0) ? ra : (mt == 1) ? rb : rc;
            #pragma unroll
            for (int s01 = 0; s01 < 2; s01++) {
                half8 v;
                #pragma unroll
                for (int j = 0; j < 8; j++) v[j] = (_Float16)A[8 * s01 + j];
                r1p[mt * 2 + s01] = v;
            }
        }
    }
    __syncthreads();    // tR visible for S4

    // ===== S4: x = relu(tR @ W1 + b1) + r1 -> B-frags only =====
    {
        half8 bw[8];
        #pragma unroll
        for (int kt = 0; kt < 8; kt++) bw[kt] = ((const half8*)W1T)[n * 16 + kt * 2 + h];
        const float bias = b1[n];
        #pragma unroll
        for (int r = 0; r < 16; r++) { acc0[r] = bias; acc1[r] = bias; acc2[r] = bias; }
        #pragma unroll
        for (int kt = 0; kt < 8; kt++) {
            acc0 = MFMA(rdB(r0, kt), bw[kt], acc0);
            acc1 = MFMA(rdB(r1, kt), bw[kt], acc1);
            acc2 = MFMA(rdB(r2, kt), bw[kt], acc2);
        }
        #pragma unroll
        for (int r = 0; r < 16; r++) {
            acc0[r] = fmaxf(acc0[r], 0.f) + (float)r1p[0 * 2 + (r >> 3)][r & 7];
            acc1[r] = fmaxf(acc1[r], 0.f) + (float)r1p[1 * 2 + (r >> 3)][r & 7];
            acc2[r] = fmaxf(acc2[r], 0.f) + (float)r1p[2 * 2 + (r >> 3)][r & 7];
        }
        buildFrags(acc0, acc1, acc2);
    }
    __syncthreads();    // all tR reads done before uR overwrites B1

    // ===== S5: u = adj @ x (B from regs) -> uR (B1) =====
    {
        #pragma unroll
        for (int r = 0; r < 16; r++) { acc0[r] = 0.f; acc1[r] = 0.f; acc2[r] = 0.f; }
        #pragma unroll
        for (int kt = 0; kt < 6; kt++) {
            const half8 bfk = __builtin_bit_cast(half8, frg[kt]);
            acc0 = MFMA(rdA(r0, kt), bfk, acc0);
            acc1 = MFMA(rdA(r1, kt), bfk, acc1);
            acc2 = MFMA(rdA(r2, kt), bfk, acc2);
        }
        writeR(acc0, acc1, acc2);
    }
    __syncthreads();    // uR visible

    // ===== S6: Y = relu(uR@W2 + adj@We + bsum) =====
    {
        half8 bw[8];
        #pragma unroll
        for (int kt = 0; kt < 8; kt++) bw[kt] = ((const half8*)W2T)[n * 16 + kt * 2 + h];
        const float bias = (float)WeT[n * 96 + 90];      // bsum[n]
        #pragma unroll
        for (int r = 0; r < 16; r++) { acc0[r] = bias; acc1[r] = bias; acc2[r] = bias; }
        #pragma unroll
        for (int kt = 0; kt < 8; kt++) {
            acc0 = MFMA(rdB(r0, kt), bw[kt], acc0);
            acc1 = MFMA(rdB(r1, kt), bw[kt], acc1);
            acc2 = MFMA(rdB(r2, kt), bw[kt], acc2);
        }
        half8 bg[6];
        #pragma unroll
        for (int kt = 0; kt < 6; kt++) bg[kt] = ((const half8*)WeT)[n * 12 + kt * 2 + h];
        #pragma unroll
        for (int kt = 0; kt < 6; kt++) {
            acc0 = MFMA(rdA(r0, kt), bg[kt], acc0);
            acc1 = MFMA(rdA(r1, kt), bg[kt], acc1);
            acc2 = MFMA(rdA(r2, kt), bg[kt], acc2);
        }
    }
    __syncthreads();    // all uR reads done before YR overwrites B1
    {
        #pragma unroll
        for (int mt = 0; mt < 3; mt++) {
            const floatx16& A = (mt == 0) ? acc0 : (mt == 1) ? acc1 : acc2;
            #pragma unroll
            for (int r = 0; r < 16; r++) {
                const int node = mt * 32 + (r & 3) + 8 * (r >> 2) + 4 * h;
                if (node < NN)
                    B1[node * 128 + (n ^ ((node & 7) << 3))] = (_Float16)fmaxf(A[r], 0.f);
            }
        }
    }
    __syncthreads();

    // ===== S7: Z = Y @ Y^T -> out (both operands from YR, swizzled reads) =====
    {
        float* outb = out + (size_t)blockIdx.x * (NN * NN);
        const int q0 = r0, q1 = r1, q2 = r2;   // clamped rows for YR reads
        auto ztile = [&](int mt, int nt) {
            const int ra_ = (mt == 0) ? q0 : (mt == 1) ? q1 : q2;
            const int rb_ = (nt == 0) ? q0 : (nt == 1) ? q1 : q2;
            floatx16 acc;
            #pragma unroll
            for (int r = 0; r < 16; r++) acc[r] = 0.f;
            #pragma unroll
            for (int kt = 0; kt < 8; kt++) {
                acc = MFMA(rdB(ra_, kt), rdB(rb_, kt), acc);
            }
            const int col = nt * 32 + p;
            if (col < NN) {
                #pragma unroll
                for (int r = 0; r < 16; r++) {
                    const int row = mt * 32 + (r & 3) + 8 * (r >> 2) + 4 * h;
                    if (row < NN) outb[row * NN + col] = acc[r];
                }
            }
        };
        if      (wv == 0) { ztile(0, 0); ztile(0, 1); ztile(0, 2); }
        else if (wv == 1) { ztile(1, 0); ztile(1, 1); }
        else if (wv == 2) { ztile(1, 2); ztile(2, 0); }
        else              { ztile(2, 1); ztile(2, 2); }
    }
}

extern "C" void kernel_launch(void* const* d_in, const int* in_sizes, int n_in,
                              void* d_out, int out_size, void* d_ws, size_t ws_size,
                              hipStream_t stream) {
    const float* adj = (const float*)d_in[0];
    const float* W0  = (const float*)d_in[1];
    const float* b0  = (const float*)d_in[2];
    const float* W1  = (const float*)d_in[3];
    const float* b1  = (const float*)d_in[4];
    const float* W2  = (const float*)d_in[5];
    const float* b2  = (const float*)d_in[6];
    const float* Wr1 = (const float*)d_in[7];
    const float* br1 = (const float*)d_in[8];
    const float* Wr2 = (const float*)d_in[9];
    const float* br2 = (const float*)d_in[10];
    float* out = (float*)d_out;
    _Float16* wts = (_Float16*)d_ws;

    float* WdF = (float*)((char*)d_ws + 139264);   // [90][128] fp32
    float* c1F = (float*)((char*)d_ws + 185344);   // [128] fp32

    prep_stage1<<<12, 1024, 0, stream>>>(W0, Wr1, b0, br1, WdF, c1F);
    prep_stage2<<<68, 1024, 0, stream>>>(W0, W1, W2, Wr2, b2, br2, WdF, c1F, wts);

    const int B = in_sizes[0] / (NN * NN);
    graphcnn_mfma<<<B, NT, 0, stream>>>(adj, wts, b0, b1, out);
}

// Round 6
// 1012.636 us; speedup vs baseline: 1.1024x; 1.1024x over previous
//
#include <hip/hip_runtime.h>

// GraphCNN fused per-graph MFMA kernel (fp16 inputs, fp32 accumulate).
// One workgroup (256 thr = 4 waves) per graph; 4 blocks/CU (LDS 40,320 B).
// R5 -> R6: ONLY change is __launch_bounds__(256,4) -> (256,3).
//   (256,4) made the allocator clamp to 64 VGPRs -> massive scratch spills
//   (hbm_bytes 0.4 -> 2.4 GB) and b128->b32 LDS read splitting (27.5M bank
//   conflicts). (256,3) gave 84 VGPRs on this same structure in R2; <=128
//   VGPRs still permits 4 waves/SIMD, so occupancy stays LDS-limited at
//   4 blocks/CU (4 x 40,448 = 161,792 <= 163,840).
// Layout (from R3): B1 [90][128] f16, row-XOR swizzle at half8 granularity
//   (slot ^= row&7); adjH split A1 [90][64] + A2 [90][32], row-XOR swizzled;
//   pad rows 90..95 eliminated (reads clamped, writes masked).
// Algebra (from R2): r1 = adj@Wd + c1, r1@Wr2 folded to adj@We + bsum.
//
// MFMA layouts (gfx950, verified learn_hip m74/m101/m120):
//   A: A[m][k], m = lane&31, k = (lane>>5)*8 + j   (8 contiguous k -> b128)
//   B: B[k][n], n = lane&31, k = (lane>>5)*8 + j
//   C/D: col = lane&31, row = (reg&3) + 8*(reg>>2) + 4*(lane>>5)

#define NN 90
#define HH 128
#define NT 256

typedef _Float16 half8 __attribute__((ext_vector_type(8)));
typedef _Float16 half2v __attribute__((ext_vector_type(2)));
typedef float floatx16 __attribute__((ext_vector_type(16)));
typedef unsigned int uint4v __attribute__((ext_vector_type(4)));

#define MFMA(a, b, c) __builtin_amdgcn_mfma_f32_32x32x16_f16((a), (b), (c), 0, 0, 0)

// ---------------- weight prep ----------------
// ws layout (f16 elems): W0T [128][96] @0 | WdT [128][96] @12288 (col90 = c1)
//   | WeT [128][96] @24576 (col90 = bsum) | W1T [128][128] @36864
//   | W2T [128][128] @53248.  End f16 @69632 (139,264 B).
// fp32 scratch: WdF [90][128] @byte 139264 ; c1F [128] @byte 185344.
__global__ void prep_stage1(const float* __restrict__ W0,
                            const float* __restrict__ Wr1,
                            const float* __restrict__ b0,
                            const float* __restrict__ br1,
                            float* __restrict__ WdF,
                            float* __restrict__ c1F)
{
    const int idx = blockIdx.x * blockDim.x + threadIdx.x;
    if (idx < NN * HH) {                 // Wd[k][n] = sum_q W0[k][q] Wr1[q][n]
        const int k = idx >> 7, nn = idx & 127;
        float s = 0.f;
        for (int q = 0; q < HH; q++) s += W0[k * HH + q] * Wr1[q * HH + nn];
        WdF[idx] = s;
    } else if (idx < NN * HH + HH) {     // c1[n] = b0@Wr1 + br1
        const int nn = idx - NN * HH;
        float s = br1[nn];
        for (int q = 0; q < HH; q++) s += b0[q] * Wr1[q * HH + nn];
        c1F[nn] = s;
    }
}

__global__ void prep_stage2(const float* __restrict__ W0,
                            const float* __restrict__ W1,
                            const float* __restrict__ W2,
                            const float* __restrict__ Wr2,
                            const float* __restrict__ b2,
                            const float* __restrict__ br2,
                            const float* __restrict__ WdF,
                            const float* __restrict__ c1F,
                            _Float16* __restrict__ ws)
{
    const int idx = blockIdx.x * blockDim.x + threadIdx.x;
    if (idx < 12288) {                       // W0T[n][k], k padded 90->96 w/ zeros
        const int nn = idx / 96, k = idx - nn * 96;
        ws[idx] = (k < NN) ? (_Float16)W0[k * HH + nn] : (_Float16)0.f;
    } else if (idx < 24576) {                // WdT[n][k]; col 90 = c1[n]
        const int j = idx - 12288;
        const int nn = j / 96, k = j - nn * 96;
        _Float16 v = (_Float16)0.f;
        if (k < NN)       v = (_Float16)WdF[k * HH + nn];
        else if (k == NN) v = (_Float16)c1F[nn];
        ws[idx] = v;
    } else if (idx < 36864) {                // WeT[n][k] = (Wd@Wr2)[k][n]; col90=bsum
        const int j = idx - 24576;
        const int nn = j / 96, k = j - nn * 96;
        _Float16 v = (_Float16)0.f;
        if (k < NN) {
            float s = 0.f;
            for (int q = 0; q < HH; q++) s += WdF[k * HH + q] * Wr2[q * HH + nn];
            v = (_Float16)s;
        } else if (k == NN) {                // bsum = b2 + br2 + c1@Wr2
            float s = b2[nn] + br2[nn];
            for (int q = 0; q < HH; q++) s += c1F[q] * Wr2[q * HH + nn];
            v = (_Float16)s;
        }
        ws[idx] = v;
    } else if (idx < 53248) {                // W1T [128][128]
        const int j = idx - 36864;
        const int nn = j >> 7, k = j & 127;
        ws[idx] = (_Float16)W1[k * HH + nn];
    } else if (idx < 69632) {                // W2T [128][128]
        const int j = idx - 53248;
        const int nn = j >> 7, k = j & 127;
        ws[idx] = (_Float16)W2[k * HH + nn];
    }
}

// ---------------- main fused kernel ----------------
__global__ __launch_bounds__(NT, 3) void graphcnn_mfma(
    const float* __restrict__ adj,
    const _Float16* __restrict__ wts,
    const float* __restrict__ b0, const float* __restrict__ b1,
    float* __restrict__ out)
{
    // LDS: A1 [90][64] swz | A2 [90][32] swz | B1 [90][128] swz (tR->uR->YR)
    __shared__ __align__(16) unsigned char smem[40320];
    _Float16* adj1 = (_Float16*)smem;                 // 11,520 B
    _Float16* adj2 = (_Float16*)(smem + 11520);       //  5,760 B
    _Float16* B1   = (_Float16*)(smem + 17280);       // 23,040 B

    const int t    = threadIdx.x;
    const int wv   = t >> 6;
    const int lane = t & 63;
    const int p    = lane & 31;
    const int h    = lane >> 5;
    const int n    = wv * 32 + p;      // hidden column owned by this thread

    const _Float16* W0T = wts;                  // [128][96]
    const _Float16* WdT = wts + 12288;          // [128][96], col90 = c1
    const _Float16* WeT = wts + 24576;          // [128][96], col90 = bsum
    const _Float16* W1T = wts + 36864;          // [128][128]
    const _Float16* W2T = wts + 53248;          // [128][128]

    // clamped A-operand rows (rows 90..95 -> 89: finite garbage, outputs masked)
    const int r0 = p;
    const int r1 = 32 + p;
    const int r2 = (64 + p > 89) ? 89 : (64 + p);

    // ---- stage adj fp32->fp16, swizzled, cols 90..95 zeroed ----
    {
        const float* Ag = adj + (size_t)blockIdx.x * (NN * NN);
        unsigned* a1u = (unsigned*)adj1;
        unsigned* a2u = (unsigned*)adj2;
        #pragma unroll
        for (int it = 0; it < 17; it++) {
            const int i = t + it * NT;          // 0..4319 = 90 rows * 48 dw
            if (i < 4320) {
                const int r = i / 48, cc = i - r * 48;
                unsigned val = 0u;
                if (cc < 45) {
                    const float2 v = *(const float2*)(Ag + r * NN + cc * 2);
                    const half2v hv = { (_Float16)v.x, (_Float16)v.y };
                    val = __builtin_bit_cast(unsigned, hv);
                }
                if (cc < 32) a1u[r * 32 + (cc ^ ((r & 7) << 2))] = val;
                else         a2u[r * 16 + ((cc - 32) ^ ((r & 3) << 2))] = val;
            }
        }
    }

    // swizzled read helpers (kt is compile-time constant at call sites)
    auto rdA = [&](int row, int kt) -> half8 {
        if (kt < 4)
            return ((const half8*)adj1)[row * 8 + (((kt * 2 + h)) ^ (row & 7))];
        else
            return ((const half8*)adj2)[row * 4 + (((kt - 4) * 2 + h) ^ (row & 3))];
    };
    auto rdB = [&](int row, int kt) -> half8 {
        return ((const half8*)B1)[row * 16 + ((kt * 2 + h) ^ (row & 7))];
    };

    // C-registers -> row-major swizzled LDS (nodes >= 90 dropped)
    auto writeR = [&](const floatx16& A0, const floatx16& A1f,
                      const floatx16& A2f) {
        #pragma unroll
        for (int mt = 0; mt < 3; mt++) {
            const floatx16& A = (mt == 0) ? A0 : (mt == 1) ? A1f : A2f;
            #pragma unroll
            for (int r = 0; r < 16; r++) {
                const int node = mt * 32 + (r & 3) + 8 * (r >> 2) + 4 * h;
                if (node < NN)
                    B1[node * 128 + (n ^ ((node & 7) << 3))] = (_Float16)A[r];
            }
        }
    };

    // C-registers -> B-fragments (for next adj@X matmul), pure in-register:
    // consumer lane (p,h) needs B[k=16kt+8h+j][n]; exchange across lane^32.
    uint4v frg[6];
    auto buildFrags = [&](const floatx16& A0, const floatx16& A1f,
                          const floatx16& A2f) {
        #pragma unroll
        for (int mt = 0; mt < 3; mt++) {
            const floatx16& A = (mt == 0) ? A0 : (mt == 1) ? A1f : A2f;
            #pragma unroll
            for (int s01 = 0; s01 < 2; s01++) {
                const int s = 8 * s01;
                const half2v x0 = { (_Float16)A[s + 0], (_Float16)A[s + 1] };
                const half2v x1 = { (_Float16)A[s + 2], (_Float16)A[s + 3] };
                const half2v y0 = { (_Float16)A[s + 4], (_Float16)A[s + 5] };
                const half2v y1 = { (_Float16)A[s + 6], (_Float16)A[s + 7] };
                const unsigned X0 = __builtin_bit_cast(unsigned, x0);
                const unsigned X1 = __builtin_bit_cast(unsigned, x1);
                const unsigned Y0 = __builtin_bit_cast(unsigned, y0);
                const unsigned Y1 = __builtin_bit_cast(unsigned, y1);
                const unsigned R0 = __shfl_xor(h ? X0 : Y0, 32, 64);
                const unsigned R1 = __shfl_xor(h ? X1 : Y1, 32, 64);
                uint4v f;
                f[0] = h ? R0 : X0;
                f[1] = h ? R1 : X1;
                f[2] = h ? Y0 : R0;
                f[3] = h ? Y1 : R1;
                frg[mt * 2 + s01] = f;
            }
        }
    };

    __syncthreads();

    floatx16 acc0, acc1, acc2;

    // ===== S1: h0 = adj @ W0 + b0 -> B-frags only (no LDS write) =====
    {
        half8 bw[6];
        #pragma unroll
        for (int kt = 0; kt < 6; kt++) bw[kt] = ((const half8*)W0T)[n * 12 + kt * 2 + h];
        const float bias = b0[n];
        #pragma unroll
        for (int r = 0; r < 16; r++) { acc0[r] = bias; acc1[r] = bias; acc2[r] = bias; }
        #pragma unroll
        for (int kt = 0; kt < 6; kt++) {
            acc0 = MFMA(rdA(r0, kt), bw[kt], acc0);
            acc1 = MFMA(rdA(r1, kt), bw[kt], acc1);
            acc2 = MFMA(rdA(r2, kt), bw[kt], acc2);
        }
        buildFrags(acc0, acc1, acc2);
    }

    // ===== S3: t = adj @ h0 (B from regs) -> tR (B1) =====
    {
        #pragma unroll
        for (int r = 0; r < 16; r++) { acc0[r] = 0.f; acc1[r] = 0.f; acc2[r] = 0.f; }
        #pragma unroll
        for (int kt = 0; kt < 6; kt++) {
            const half8 bfk = __builtin_bit_cast(half8, frg[kt]);
            acc0 = MFMA(rdA(r0, kt), bfk, acc0);
            acc1 = MFMA(rdA(r1, kt), bfk, acc1);
            acc2 = MFMA(rdA(r2, kt), bfk, acc2);
        }
        writeR(acc0, acc1, acc2);
    }

    // ===== S2': r1 = adj @ Wd + c1 -> packed fp16 regs =====
    half8 r1p[6];
    {
        half8 bw[6];
        #pragma unroll
        for (int kt = 0; kt < 6; kt++) bw[kt] = ((const half8*)WdT)[n * 12 + kt * 2 + h];
        const float bias = (float)WdT[n * 96 + 90];      // c1[n]
        floatx16 ra, rb, rc;
        #pragma unroll
        for (int r = 0; r < 16; r++) { ra[r] = bias; rb[r] = bias; rc[r] = bias; }
        #pragma unroll
        for (int kt = 0; kt < 6; kt++) {
            ra = MFMA(rdA(r0, kt), bw[kt], ra);
            rb = MFMA(rdA(r1, kt), bw[kt], rb);
            rc = MFMA(rdA(r2, kt), bw[kt], rc);
        }
        #pragma unroll
        for (int mt = 0; mt < 3; mt++) {
            const floatx16& A = (mt == 0) ? ra : (mt == 1) ? rb : rc;
            #pragma unroll
            for (int s01 = 0; s01 < 2; s01++) {
                half8 v;
                #pragma unroll
                for (int j = 0; j < 8; j++) v[j] = (_Float16)A[8 * s01 + j];
                r1p[mt * 2 + s01] = v;
            }
        }
    }
    __syncthreads();    // tR visible for S4

    // ===== S4: x = relu(tR @ W1 + b1) + r1 -> B-frags only =====
    {
        half8 bw[8];
        #pragma unroll
        for (int kt = 0; kt < 8; kt++) bw[kt] = ((const half8*)W1T)[n * 16 + kt * 2 + h];
        const float bias = b1[n];
        #pragma unroll
        for (int r = 0; r < 16; r++) { acc0[r] = bias; acc1[r] = bias; acc2[r] = bias; }
        #pragma unroll
        for (int kt = 0; kt < 8; kt++) {
            acc0 = MFMA(rdB(r0, kt), bw[kt], acc0);
            acc1 = MFMA(rdB(r1, kt), bw[kt], acc1);
            acc2 = MFMA(rdB(r2, kt), bw[kt], acc2);
        }
        #pragma unroll
        for (int r = 0; r < 16; r++) {
            acc0[r] = fmaxf(acc0[r], 0.f) + (float)r1p[0 * 2 + (r >> 3)][r & 7];
            acc1[r] = fmaxf(acc1[r], 0.f) + (float)r1p[1 * 2 + (r >> 3)][r & 7];
            acc2[r] = fmaxf(acc2[r], 0.f) + (float)r1p[2 * 2 + (r >> 3)][r & 7];
        }
        buildFrags(acc0, acc1, acc2);
    }
    __syncthreads();    // all tR reads done before uR overwrites B1

    // ===== S5: u = adj @ x (B from regs) -> uR (B1) =====
    {
        #pragma unroll
        for (int r = 0; r < 16; r++) { acc0[r] = 0.f; acc1[r] = 0.f; acc2[r] = 0.f; }
        #pragma unroll
        for (int kt = 0; kt < 6; kt++) {
            const half8 bfk = __builtin_bit_cast(half8, frg[kt]);
            acc0 = MFMA(rdA(r0, kt), bfk, acc0);
            acc1 = MFMA(rdA(r1, kt), bfk, acc1);
            acc2 = MFMA(rdA(r2, kt), bfk, acc2);
        }
        writeR(acc0, acc1, acc2);
    }
    __syncthreads();    // uR visible

    // ===== S6: Y = relu(uR@W2 + adj@We + bsum) =====
    {
        half8 bw[8];
        #pragma unroll
        for (int kt = 0; kt < 8; kt++) bw[kt] = ((const half8*)W2T)[n * 16 + kt * 2 + h];
        const float bias = (float)WeT[n * 96 + 90];      // bsum[n]
        #pragma unroll
        for (int r = 0; r < 16; r++) { acc0[r] = bias; acc1[r] = bias; acc2[r] = bias; }
        #pragma unroll
        for (int kt = 0; kt < 8; kt++) {
            acc0 = MFMA(rdB(r0, kt), bw[kt], acc0);
            acc1 = MFMA(rdB(r1, kt), bw[kt], acc1);
            acc2 = MFMA(rdB(r2, kt), bw[kt], acc2);
        }
        half8 bg[6];
        #pragma unroll
        for (int kt = 0; kt < 6; kt++) bg[kt] = ((const half8*)WeT)[n * 12 + kt * 2 + h];
        #pragma unroll
        for (int kt = 0; kt < 6; kt++) {
            acc0 = MFMA(rdA(r0, kt), bg[kt], acc0);
            acc1 = MFMA(rdA(r1, kt), bg[kt], acc1);
            acc2 = MFMA(rdA(r2, kt), bg[kt], acc2);
        }
    }
    __syncthreads();    // all uR reads done before YR overwrites B1
    {
        #pragma unroll
        for (int mt = 0; mt < 3; mt++) {
            const floatx16& A = (mt == 0) ? acc0 : (mt == 1) ? acc1 : acc2;
            #pragma unroll
            for (int r = 0; r < 16; r++) {
                const int node = mt * 32 + (r & 3) + 8 * (r >> 2) + 4 * h;
                if (node < NN)
                    B1[node * 128 + (n ^ ((node & 7) << 3))] = (_Float16)fmaxf(A[r], 0.f);
            }
        }
    }
    __syncthreads();

    // ===== S7: Z = Y @ Y^T -> out (both operands from YR, swizzled reads) =====
    {
        float* outb = out + (size_t)blockIdx.x * (NN * NN);
        const int q0 = r0, q1 = r1, q2 = r2;   // clamped rows for YR reads
        auto ztile = [&](int mt, int nt) {
            const int ra_ = (mt == 0) ? q0 : (mt == 1) ? q1 : q2;
            const int rb_ = (nt == 0) ? q0 : (nt == 1) ? q1 : q2;
            floatx16 acc;
            #pragma unroll
            for (int r = 0; r < 16; r++) acc[r] = 0.f;
            #pragma unroll
            for (int kt = 0; kt < 8; kt++) {
                acc = MFMA(rdB(ra_, kt), rdB(rb_, kt), acc);
            }
            const int col = nt * 32 + p;
            if (col < NN) {
                #pragma unroll
                for (int r = 0; r < 16; r++) {
                    const int row = mt * 32 + (r & 3) + 8 * (r >> 2) + 4 * h;
                    if (row < NN) outb[row * NN + col] = acc[r];
                }
            }
        };
        if      (wv == 0) { ztile(0, 0); ztile(0, 1); ztile(0, 2); }
        else if (wv == 1) { ztile(1, 0); ztile(1, 1); }
        else if (wv == 2) { ztile(1, 2); ztile(2, 0); }
        else              { ztile(2, 1); ztile(2, 2); }
    }
}

extern "C" void kernel_launch(void* const* d_in, const int* in_sizes, int n_in,
                              void* d_out, int out_size, void* d_ws, size_t ws_size,
                              hipStream_t stream) {
    const float* adj = (const float*)d_in[0];
    const float* W0  = (const float*)d_in[1];
    const float* b0  = (const float*)d_in[2];
    const float* W1  = (const float*)d_in[3];
    const float* b1  = (const float*)d_in[4];
    const float* W2  = (const float*)d_in[5];
    const float* b2  = (const float*)d_in[6];
    const float* Wr1 = (const float*)d_in[7];
    const float* br1 = (const float*)d_in[8];
    const float* Wr2 = (const float*)d_in[9];
    const float* br2 = (const float*)d_in[10];
    float* out = (float*)d_out;
    _Float16* wts = (_Float16*)d_ws;

    float* WdF = (float*)((char*)d_ws + 139264);   // [90][128] fp32
    float* c1F = (float*)((char*)d_ws + 185344);   // [128] fp32

    prep_stage1<<<12, 1024, 0, stream>>>(W0, Wr1, b0, br1, WdF, c1F);
    prep_stage2<<<68, 1024, 0, stream>>>(W0, W1, W2, Wr2, b2, br2, WdF, c1F, wts);

    const int B = in_sizes[0] / (NN * NN);
    graphcnn_mfma<<<B, NT, 0, stream>>>(adj, wts, b0, b1, out);
}

// Round 7
// 741.255 us; speedup vs baseline: 1.5060x; 1.3661x over previous
//
#include <hip/hip_runtime.h>

// GraphCNN fused per-graph MFMA kernel (fp16 inputs, fp32 accumulate).
// One workgroup (256 thr = 4 waves) per graph; target 4 blocks/CU (LDS 40,320 B).
// R6 -> R7: ONLY change is __launch_bounds__(256,3) -> (256,2).
//   Allocator per-wave VGPR cap behaves as floor(256/min_waves) (R1/R2/R5/R6
//   evidence: caps 128/85/64). The R3 swizzled layout needs slightly more
//   than 85 regs -> at bound 3 it spilled (~80 dw/thread: +1.2 GB scratch
//   traffic, 27.5M bank conflicts from b128->b32 splitting) while showing
//   VGPR_Count=84 (at-cap). Bound 2 raises the cap to 128; the ~100-reg
//   working set fits spill-free. Residency is NOT capped by the bound:
//   VGPR<=128 still admits 4 waves/SIMD, so LDS remains the limiter at
//   4 blocks/CU (4 x 40,448 = 161,792 <= 163,840).
// Layout (from R3): B1 [90][128] f16, row-XOR swizzle at half8 granularity
//   (slot ^= row&7); adjH split A1 [90][64] + A2 [90][32], row-XOR swizzled;
//   pad rows 90..95 eliminated (reads clamped, writes masked).
// Algebra (from R2): r1 = adj@Wd + c1, r1@Wr2 folded to adj@We + bsum.
//
// MFMA layouts (gfx950, verified learn_hip m74/m101/m120):
//   A: A[m][k], m = lane&31, k = (lane>>5)*8 + j   (8 contiguous k -> b128)
//   B: B[k][n], n = lane&31, k = (lane>>5)*8 + j
//   C/D: col = lane&31, row = (reg&3) + 8*(reg>>2) + 4*(lane>>5)

#define NN 90
#define HH 128
#define NT 256

typedef _Float16 half8 __attribute__((ext_vector_type(8)));
typedef _Float16 half2v __attribute__((ext_vector_type(2)));
typedef float floatx16 __attribute__((ext_vector_type(16)));
typedef unsigned int uint4v __attribute__((ext_vector_type(4)));

#define MFMA(a, b, c) __builtin_amdgcn_mfma_f32_32x32x16_f16((a), (b), (c), 0, 0, 0)

// ---------------- weight prep ----------------
// ws layout (f16 elems): W0T [128][96] @0 | WdT [128][96] @12288 (col90 = c1)
//   | WeT [128][96] @24576 (col90 = bsum) | W1T [128][128] @36864
//   | W2T [128][128] @53248.  End f16 @69632 (139,264 B).
// fp32 scratch: WdF [90][128] @byte 139264 ; c1F [128] @byte 185344.
__global__ void prep_stage1(const float* __restrict__ W0,
                            const float* __restrict__ Wr1,
                            const float* __restrict__ b0,
                            const float* __restrict__ br1,
                            float* __restrict__ WdF,
                            float* __restrict__ c1F)
{
    const int idx = blockIdx.x * blockDim.x + threadIdx.x;
    if (idx < NN * HH) {                 // Wd[k][n] = sum_q W0[k][q] Wr1[q][n]
        const int k = idx >> 7, nn = idx & 127;
        float s = 0.f;
        for (int q = 0; q < HH; q++) s += W0[k * HH + q] * Wr1[q * HH + nn];
        WdF[idx] = s;
    } else if (idx < NN * HH + HH) {     // c1[n] = b0@Wr1 + br1
        const int nn = idx - NN * HH;
        float s = br1[nn];
        for (int q = 0; q < HH; q++) s += b0[q] * Wr1[q * HH + nn];
        c1F[nn] = s;
    }
}

__global__ void prep_stage2(const float* __restrict__ W0,
                            const float* __restrict__ W1,
                            const float* __restrict__ W2,
                            const float* __restrict__ Wr2,
                            const float* __restrict__ b2,
                            const float* __restrict__ br2,
                            const float* __restrict__ WdF,
                            const float* __restrict__ c1F,
                            _Float16* __restrict__ ws)
{
    const int idx = blockIdx.x * blockDim.x + threadIdx.x;
    if (idx < 12288) {                       // W0T[n][k], k padded 90->96 w/ zeros
        const int nn = idx / 96, k = idx - nn * 96;
        ws[idx] = (k < NN) ? (_Float16)W0[k * HH + nn] : (_Float16)0.f;
    } else if (idx < 24576) {                // WdT[n][k]; col 90 = c1[n]
        const int j = idx - 12288;
        const int nn = j / 96, k = j - nn * 96;
        _Float16 v = (_Float16)0.f;
        if (k < NN)       v = (_Float16)WdF[k * HH + nn];
        else if (k == NN) v = (_Float16)c1F[nn];
        ws[idx] = v;
    } else if (idx < 36864) {                // WeT[n][k] = (Wd@Wr2)[k][n]; col90=bsum
        const int j = idx - 24576;
        const int nn = j / 96, k = j - nn * 96;
        _Float16 v = (_Float16)0.f;
        if (k < NN) {
            float s = 0.f;
            for (int q = 0; q < HH; q++) s += WdF[k * HH + q] * Wr2[q * HH + nn];
            v = (_Float16)s;
        } else if (k == NN) {                // bsum = b2 + br2 + c1@Wr2
            float s = b2[nn] + br2[nn];
            for (int q = 0; q < HH; q++) s += c1F[q] * Wr2[q * HH + nn];
            v = (_Float16)s;
        }
        ws[idx] = v;
    } else if (idx < 53248) {                // W1T [128][128]
        const int j = idx - 36864;
        const int nn = j >> 7, k = j & 127;
        ws[idx] = (_Float16)W1[k * HH + nn];
    } else if (idx < 69632) {                // W2T [128][128]
        const int j = idx - 53248;
        const int nn = j >> 7, k = j & 127;
        ws[idx] = (_Float16)W2[k * HH + nn];
    }
}

// ---------------- main fused kernel ----------------
__global__ __launch_bounds__(NT, 2) void graphcnn_mfma(
    const float* __restrict__ adj,
    const _Float16* __restrict__ wts,
    const float* __restrict__ b0, const float* __restrict__ b1,
    float* __restrict__ out)
{
    // LDS: A1 [90][64] swz | A2 [90][32] swz | B1 [90][128] swz (tR->uR->YR)
    __shared__ __align__(16) unsigned char smem[40320];
    _Float16* adj1 = (_Float16*)smem;                 // 11,520 B
    _Float16* adj2 = (_Float16*)(smem + 11520);       //  5,760 B
    _Float16* B1   = (_Float16*)(smem + 17280);       // 23,040 B

    const int t    = threadIdx.x;
    const int wv   = t >> 6;
    const int lane = t & 63;
    const int p    = lane & 31;
    const int h    = lane >> 5;
    const int n    = wv * 32 + p;      // hidden column owned by this thread

    const _Float16* W0T = wts;                  // [128][96]
    const _Float16* WdT = wts + 12288;          // [128][96], col90 = c1
    const _Float16* WeT = wts + 24576;          // [128][96], col90 = bsum
    const _Float16* W1T = wts + 36864;          // [128][128]
    const _Float16* W2T = wts + 53248;          // [128][128]

    // clamped A-operand rows (rows 90..95 -> 89: finite garbage, outputs masked)
    const int r0 = p;
    const int r1 = 32 + p;
    const int r2 = (64 + p > 89) ? 89 : (64 + p);

    // ---- stage adj fp32->fp16, swizzled, cols 90..95 zeroed ----
    {
        const float* Ag = adj + (size_t)blockIdx.x * (NN * NN);
        unsigned* a1u = (unsigned*)adj1;
        unsigned* a2u = (unsigned*)adj2;
        #pragma unroll
        for (int it = 0; it < 17; it++) {
            const int i = t + it * NT;          // 0..4319 = 90 rows * 48 dw
            if (i < 4320) {
                const int r = i / 48, cc = i - r * 48;
                unsigned val = 0u;
                if (cc < 45) {
                    const float2 v = *(const float2*)(Ag + r * NN + cc * 2);
                    const half2v hv = { (_Float16)v.x, (_Float16)v.y };
                    val = __builtin_bit_cast(unsigned, hv);
                }
                if (cc < 32) a1u[r * 32 + (cc ^ ((r & 7) << 2))] = val;
                else         a2u[r * 16 + ((cc - 32) ^ ((r & 3) << 2))] = val;
            }
        }
    }

    // swizzled read helpers (kt is compile-time constant at call sites)
    auto rdA = [&](int row, int kt) -> half8 {
        if (kt < 4)
            return ((const half8*)adj1)[row * 8 + (((kt * 2 + h)) ^ (row & 7))];
        else
            return ((const half8*)adj2)[row * 4 + (((kt - 4) * 2 + h) ^ (row & 3))];
    };
    auto rdB = [&](int row, int kt) -> half8 {
        return ((const half8*)B1)[row * 16 + ((kt * 2 + h) ^ (row & 7))];
    };

    // C-registers -> row-major swizzled LDS (nodes >= 90 dropped)
    auto writeR = [&](const floatx16& A0, const floatx16& A1f,
                      const floatx16& A2f) {
        #pragma unroll
        for (int mt = 0; mt < 3; mt++) {
            const floatx16& A = (mt == 0) ? A0 : (mt == 1) ? A1f : A2f;
            #pragma unroll
            for (int r = 0; r < 16; r++) {
                const int node = mt * 32 + (r & 3) + 8 * (r >> 2) + 4 * h;
                if (node < NN)
                    B1[node * 128 + (n ^ ((node & 7) << 3))] = (_Float16)A[r];
            }
        }
    };

    // C-registers -> B-fragments (for next adj@X matmul), pure in-register:
    // consumer lane (p,h) needs B[k=16kt+8h+j][n]; exchange across lane^32.
    uint4v frg[6];
    auto buildFrags = [&](const floatx16& A0, const floatx16& A1f,
                          const floatx16& A2f) {
        #pragma unroll
        for (int mt = 0; mt < 3; mt++) {
            const floatx16& A = (mt == 0) ? A0 : (mt == 1) ? A1f : A2f;
            #pragma unroll
            for (int s01 = 0; s01 < 2; s01++) {
                const int s = 8 * s01;
                const half2v x0 = { (_Float16)A[s + 0], (_Float16)A[s + 1] };
                const half2v x1 = { (_Float16)A[s + 2], (_Float16)A[s + 3] };
                const half2v y0 = { (_Float16)A[s + 4], (_Float16)A[s + 5] };
                const half2v y1 = { (_Float16)A[s + 6], (_Float16)A[s + 7] };
                const unsigned X0 = __builtin_bit_cast(unsigned, x0);
                const unsigned X1 = __builtin_bit_cast(unsigned, x1);
                const unsigned Y0 = __builtin_bit_cast(unsigned, y0);
                const unsigned Y1 = __builtin_bit_cast(unsigned, y1);
                const unsigned R0 = __shfl_xor(h ? X0 : Y0, 32, 64);
                const unsigned R1 = __shfl_xor(h ? X1 : Y1, 32, 64);
                uint4v f;
                f[0] = h ? R0 : X0;
                f[1] = h ? R1 : X1;
                f[2] = h ? Y0 : R0;
                f[3] = h ? Y1 : R1;
                frg[mt * 2 + s01] = f;
            }
        }
    };

    __syncthreads();

    floatx16 acc0, acc1, acc2;

    // ===== S1: h0 = adj @ W0 + b0 -> B-frags only (no LDS write) =====
    {
        half8 bw[6];
        #pragma unroll
        for (int kt = 0; kt < 6; kt++) bw[kt] = ((const half8*)W0T)[n * 12 + kt * 2 + h];
        const float bias = b0[n];
        #pragma unroll
        for (int r = 0; r < 16; r++) { acc0[r] = bias; acc1[r] = bias; acc2[r] = bias; }
        #pragma unroll
        for (int kt = 0; kt < 6; kt++) {
            acc0 = MFMA(rdA(r0, kt), bw[kt], acc0);
            acc1 = MFMA(rdA(r1, kt), bw[kt], acc1);
            acc2 = MFMA(rdA(r2, kt), bw[kt], acc2);
        }
        buildFrags(acc0, acc1, acc2);
    }

    // ===== S3: t = adj @ h0 (B from regs) -> tR (B1) =====
    {
        #pragma unroll
        for (int r = 0; r < 16; r++) { acc0[r] = 0.f; acc1[r] = 0.f; acc2[r] = 0.f; }
        #pragma unroll
        for (int kt = 0; kt < 6; kt++) {
            const half8 bfk = __builtin_bit_cast(half8, frg[kt]);
            acc0 = MFMA(rdA(r0, kt), bfk, acc0);
            acc1 = MFMA(rdA(r1, kt), bfk, acc1);
            acc2 = MFMA(rdA(r2, kt), bfk, acc2);
        }
        writeR(acc0, acc1, acc2);
    }

    // ===== S2': r1 = adj @ Wd + c1 -> packed fp16 regs =====
    half8 r1p[6];
    {
        half8 bw[6];
        #pragma unroll
        for (int kt = 0; kt < 6; kt++) bw[kt] = ((const half8*)WdT)[n * 12 + kt * 2 + h];
        const float bias = (float)WdT[n * 96 + 90];      // c1[n]
        floatx16 ra, rb, rc;
        #pragma unroll
        for (int r = 0; r < 16; r++) { ra[r] = bias; rb[r] = bias; rc[r] = bias; }
        #pragma unroll
        for (int kt = 0; kt < 6; kt++) {
            ra = MFMA(rdA(r0, kt), bw[kt], ra);
            rb = MFMA(rdA(r1, kt), bw[kt], rb);
            rc = MFMA(rdA(r2, kt), bw[kt], rc);
        }
        #pragma unroll
        for (int mt = 0; mt < 3; mt++) {
            const floatx16& A = (mt == 0) ? ra : (mt == 1) ? rb : rc;
            #pragma unroll
            for (int s01 = 0; s01 < 2; s01++) {
                half8 v;
                #pragma unroll
                for (int j = 0; j < 8; j++) v[j] = (_Float16)A[8 * s01 + j];
                r1p[mt * 2 + s01] = v;
            }
        }
    }
    __syncthreads();    // tR visible for S4

    // ===== S4: x = relu(tR @ W1 + b1) + r1 -> B-frags only =====
    {
        half8 bw[8];
        #pragma unroll
        for (int kt = 0; kt < 8; kt++) bw[kt] = ((const half8*)W1T)[n * 16 + kt * 2 + h];
        const float bias = b1[n];
        #pragma unroll
        for (int r = 0; r < 16; r++) { acc0[r] = bias; acc1[r] = bias; acc2[r] = bias; }
        #pragma unroll
        for (int kt = 0; kt < 8; kt++) {
            acc0 = MFMA(rdB(r0, kt), bw[kt], acc0);
            acc1 = MFMA(rdB(r1, kt), bw[kt], acc1);
            acc2 = MFMA(rdB(r2, kt), bw[kt], acc2);
        }
        #pragma unroll
        for (int r = 0; r < 16; r++) {
            acc0[r] = fmaxf(acc0[r], 0.f) + (float)r1p[0 * 2 + (r >> 3)][r & 7];
            acc1[r] = fmaxf(acc1[r], 0.f) + (float)r1p[1 * 2 + (r >> 3)][r & 7];
            acc2[r] = fmaxf(acc2[r], 0.f) + (float)r1p[2 * 2 + (r >> 3)][r & 7];
        }
        buildFrags(acc0, acc1, acc2);
    }
    __syncthreads();    // all tR reads done before uR overwrites B1

    // ===== S5: u = adj @ x (B from regs) -> uR (B1) =====
    {
        #pragma unroll
        for (int r = 0; r < 16; r++) { acc0[r] = 0.f; acc1[r] = 0.f; acc2[r] = 0.f; }
        #pragma unroll
        for (int kt = 0; kt < 6; kt++) {
            const half8 bfk = __builtin_bit_cast(half8, frg[kt]);
            acc0 = MFMA(rdA(r0, kt), bfk, acc0);
            acc1 = MFMA(rdA(r1, kt), bfk, acc1);
            acc2 = MFMA(rdA(r2, kt), bfk, acc2);
        }
        writeR(acc0, acc1, acc2);
    }
    __syncthreads();    // uR visible

    // ===== S6: Y = relu(uR@W2 + adj@We + bsum) =====
    {
        half8 bw[8];
        #pragma unroll
        for (int kt = 0; kt < 8; kt++) bw[kt] = ((const half8*)W2T)[n * 16 + kt * 2 + h];
        const float bias = (float)WeT[n * 96 + 90];      // bsum[n]
        #pragma unroll
        for (int r = 0; r < 16; r++) { acc0[r] = bias; acc1[r] = bias; acc2[r] = bias; }
        #pragma unroll
        for (int kt = 0; kt < 8; kt++) {
            acc0 = MFMA(rdB(r0, kt), bw[kt], acc0);
            acc1 = MFMA(rdB(r1, kt), bw[kt], acc1);
            acc2 = MFMA(rdB(r2, kt), bw[kt], acc2);
        }
        half8 bg[6];
        #pragma unroll
        for (int kt = 0; kt < 6; kt++) bg[kt] = ((const half8*)WeT)[n * 12 + kt * 2 + h];
        #pragma unroll
        for (int kt = 0; kt < 6; kt++) {
            acc0 = MFMA(rdA(r0, kt), bg[kt], acc0);
            acc1 = MFMA(rdA(r1, kt), bg[kt], acc1);
            acc2 = MFMA(rdA(r2, kt), bg[kt], acc2);
        }
    }
    __syncthreads();    // all uR reads done before YR overwrites B1
    {
        #pragma unroll
        for (int mt = 0; mt < 3; mt++) {
            const floatx16& A = (mt == 0) ? acc0 : (mt == 1) ? acc1 : acc2;
            #pragma unroll
            for (int r = 0; r < 16; r++) {
                const int node = mt * 32 + (r & 3) + 8 * (r >> 2) + 4 * h;
                if (node < NN)
                    B1[node * 128 + (n ^ ((node & 7) << 3))] = (_Float16)fmaxf(A[r], 0.f);
            }
        }
    }
    __syncthreads();

    // ===== S7: Z = Y @ Y^T -> out (both operands from YR, swizzled reads) =====
    {
        float* outb = out + (size_t)blockIdx.x * (NN * NN);
        const int q0 = r0, q1 = r1, q2 = r2;   // clamped rows for YR reads
        auto ztile = [&](int mt, int nt) {
            const int ra_ = (mt == 0) ? q0 : (mt == 1) ? q1 : q2;
            const int rb_ = (nt == 0) ? q0 : (nt == 1) ? q1 : q2;
            floatx16 acc;
            #pragma unroll
            for (int r = 0; r < 16; r++) acc[r] = 0.f;
            #pragma unroll
            for (int kt = 0; kt < 8; kt++) {
                acc = MFMA(rdB(ra_, kt), rdB(rb_, kt), acc);
            }
            const int col = nt * 32 + p;
            if (col < NN) {
                #pragma unroll
                for (int r = 0; r < 16; r++) {
                    const int row = mt * 32 + (r & 3) + 8 * (r >> 2) + 4 * h;
                    if (row < NN) outb[row * NN + col] = acc[r];
                }
            }
        };
        if      (wv == 0) { ztile(0, 0); ztile(0, 1); ztile(0, 2); }
        else if (wv == 1) { ztile(1, 0); ztile(1, 1); }
        else if (wv == 2) { ztile(1, 2); ztile(2, 0); }
        else              { ztile(2, 1); ztile(2, 2); }
    }
}

extern "C" void kernel_launch(void* const* d_in, const int* in_sizes, int n_in,
                              void* d_out, int out_size, void* d_ws, size_t ws_size,
                              hipStream_t stream) {
    const float* adj = (const float*)d_in[0];
    const float* W0  = (const float*)d_in[1];
    const float* b0  = (const float*)d_in[2];
    const float* W1  = (const float*)d_in[3];
    const float* b1  = (const float*)d_in[4];
    const float* W2  = (const float*)d_in[5];
    const float* b2  = (const float*)d_in[6];
    const float* Wr1 = (const float*)d_in[7];
    const float* br1 = (const float*)d_in[8];
    const float* Wr2 = (const float*)d_in[9];
    const float* br2 = (const float*)d_in[10];
    float* out = (float*)d_out;
    _Float16* wts = (_Float16*)d_ws;

    float* WdF = (float*)((char*)d_ws + 139264);   // [90][128] fp32
    float* c1F = (float*)((char*)d_ws + 185344);   // [128] fp32

    prep_stage1<<<12, 1024, 0, stream>>>(W0, Wr1, b0, br1, WdF, c1F);
    prep_stage2<<<68, 1024, 0, stream>>>(W0, W1, W2, Wr2, b2, br2, WdF, c1F, wts);

    const int B = in_sizes[0] / (NN * NN);
    graphcnn_mfma<<<B, NT, 0, stream>>>(adj, wts, b0, b1, out);
}